// Round 7
// baseline (69.986 us; speedup 1.0000x reference)
//
#include <hip/hip_runtime.h>

#define BLK 256
#define VPT 4
#define RB (BLK * VPT)   // 1024 rows per block

typedef float v4f __attribute__((ext_vector_type(4)));

// ---------------------------------------------------------------------------
// k0: zero the roi accumulator mirror in d_ws (fast memory).
// ---------------------------------------------------------------------------
__global__ __launch_bounds__(BLK) void k0_zero(float* __restrict__ roi_ws, int n)
{
    const int t = blockIdx.x * BLK + threadIdx.x;
    if (t < n) roi_ws[t] = 0.0f;
}

// ---------------------------------------------------------------------------
// k3: copy the accumulated roi mirror (d_ws) into d_out.
// ---------------------------------------------------------------------------
__global__ __launch_bounds__(BLK) void k3_copy(const float* __restrict__ roi_ws,
                                               float* __restrict__ roi, int n)
{
    const int t = blockIdx.x * BLK + threadIdx.x;
    if (t < n) roi[t] = roi_ws[t];
}

// ---------------------------------------------------------------------------
// kA: fused. Per region of 1024 rows:
//   1) mask 4 voxels/thread vs 64 boxes (one ds_read_b128 per box, packed)
//   2) sel nt-store + block-local LDS compaction
//   3) skip nt-store burst (64 MB total) -- issued BEFORE roi phase
//   4) ROI phase: gather conv/feature rows of hits, atomicAdd into roi_ws
// ---------------------------------------------------------------------------
__global__ __launch_bounds__(BLK) void kA_fused(
    const int* __restrict__ coords,      // [N,3]
    const int* __restrict__ batch_idx,   // [N]
    const float* __restrict__ features,  // [N,32]
    const float* __restrict__ conv,      // [N,64]
    const int* __restrict__ box_batch,   // [M]
    const int* __restrict__ box_min,     // [M,3]
    const int* __restrict__ box_max,     // [M,3]
    float* __restrict__ skip_out,        // [N,32]
    float* __restrict__ sel_out,         // [N]
    float* __restrict__ roi_ws,          // [M,96] accumulator in d_ws
    int N, int M)
{
    __shared__ int4 sbox[64];            // {lo|hi<<16, y0|y1<<16, z0|z1<<16, -}
    __shared__ float ssel[RB];
    __shared__ int svox[RB];
    __shared__ unsigned long long smask[RB];
    __shared__ int wc[16];
    __shared__ int wb[16];
    __shared__ int scnt;

    const int t = threadIdx.x;
    const int lane = t & 63;
    const int wid = t >> 6;
    const int base = blockIdx.x * RB;

    // Stage packed box bounds; pad m>=M with an empty range (lo=0xFFFF,hi=0).
    if (t < 64) {
        int w0 = 0xFFFF, w1 = 0, w2 = 0;
        if (t < M) {
            const int b = box_batch[t];
            const int lo = (b << 9) | box_min[t * 3 + 0];
            const int hi = (b << 9) | box_max[t * 3 + 0];
            w0 = lo | (hi << 16);
            w1 = box_min[t * 3 + 1] | (box_max[t * 3 + 1] << 16);
            w2 = box_min[t * 3 + 2] | (box_max[t * 3 + 2] << 16);
        }
        sbox[t] = make_int4(w0, w1, w2, 0);
    }
    __syncthreads();

    // ---- mask: 4 voxels per thread, one b128 per box per 4 tests ----
    int px[VPT], py[VPT], pz[VPT];
    unsigned long long mask[VPT];
    #pragma unroll
    for (int v = 0; v < VPT; ++v) {
        const int i = base + v * BLK + t;
        mask[v] = 0ull;
        if (i < N) {
            const int x = coords[(size_t)i * 3 + 0];
            const int y = coords[(size_t)i * 3 + 1];
            const int z = coords[(size_t)i * 3 + 2];
            px[v] = (batch_idx[i] << 9) | x;
            py[v] = y;  pz[v] = z;
        } else {
            px[v] = -1;  py[v] = -1;  pz[v] = -1;
        }
    }
    #pragma unroll 8
    for (int m = 0; m < 64; ++m) {
        const int4 q = sbox[m];
        const int lo = q.x & 0xFFFF, hi = ((unsigned)q.x) >> 16;
        const int y0 = q.y & 0xFFFF, y1 = ((unsigned)q.y) >> 16;
        const int z0 = q.z & 0xFFFF, z1 = ((unsigned)q.z) >> 16;
        #pragma unroll
        for (int v = 0; v < VPT; ++v) {
            const bool ins = (px[v] >= lo) & (px[v] < hi)
                           & (py[v] >= y0) & (py[v] < y1)
                           & (pz[v] >= z0) & (pz[v] < z1);
            mask[v] |= ins ? (1ull << m) : 0ull;
        }
    }

    // selection output (nt) + LDS flags
    #pragma unroll
    for (int v = 0; v < VPT; ++v) {
        const int i = base + v * BLK + t;
        const float s = mask[v] ? 1.0f : 0.0f;
        ssel[v * BLK + t] = s;
        if (i < N) __builtin_nontemporal_store(s, &sel_out[i]);
    }

    // ---- block-local compaction into LDS (deterministic, no atomics) ----
    unsigned long long ball[VPT];
    #pragma unroll
    for (int v = 0; v < VPT; ++v) ball[v] = __ballot(mask[v] != 0ull);
    if (lane == 0) {
        #pragma unroll
        for (int v = 0; v < VPT; ++v) wc[wid * VPT + v] = __popcll(ball[v]);
    }
    __syncthreads();
    if (t == 0) {
        int s = 0;
        #pragma unroll
        for (int k = 0; k < 16; ++k) { wb[k] = s; s += wc[k]; }
        scnt = s;
    }
    __syncthreads();
    #pragma unroll
    for (int v = 0; v < VPT; ++v) {
        if (mask[v]) {
            const int pos = wb[wid * VPT + v]
                          + __popcll(ball[v] & ((1ull << lane) - 1ull));
            svox[pos] = base + v * BLK + t;
            smask[pos] = mask[v];
        }
    }
    __syncthreads();

    // ---- skip store burst first (drains while ROI phase runs) ----
    const int nrows = min(RB, N - base);
    if (nrows > 0) {
        const v4f* __restrict__ f4 = (const v4f*)features;
        v4f* __restrict__ s4 = (v4f*)skip_out;
        const int total = nrows * 8;           // 8 float4 per 32-float row
        for (int j = t; j < total; j += BLK) {
            const int r = j >> 3;
            const size_t idx = (size_t)base * 8 + j;
            v4f vv = {0.f, 0.f, 0.f, 0.f};
            if (ssel[r] != 0.0f) vv = f4[idx];
            __builtin_nontemporal_store(vv, &s4[idx]);
        }
    }

    // ---- ROI phase: 4 waves split this block's hits; atomics into d_ws ----
    const int cnt = scnt;
    for (int j = wid; j < cnt; j += 4) {
        const int vox = svox[j];
        unsigned long long mk = smask[j];
        const float cval = conv[(size_t)vox * 64 + lane];
        const float fval = (lane < 32) ? features[(size_t)vox * 32 + lane] : 0.0f;
        while (mk) {
            const int m = __ffsll((long long)mk) - 1;
            mk &= mk - 1;
            atomicAdd(&roi_ws[m * 96 + lane], cval);
            if (lane < 32) atomicAdd(&roi_ws[m * 96 + 64 + lane], fval);
        }
    }
}

extern "C" void kernel_launch(void* const* d_in, const int* in_sizes, int n_in,
                              void* d_out, int out_size, void* d_ws, size_t ws_size,
                              hipStream_t stream)
{
    const int* coords      = (const int*)d_in[0];
    const int* batch_idx   = (const int*)d_in[1];
    const float* features  = (const float*)d_in[2];
    const float* conv      = (const float*)d_in[3];
    const int* box_batch   = (const int*)d_in[4];
    const int* box_min     = (const int*)d_in[5];
    const int* box_max     = (const int*)d_in[6];

    const int N  = in_sizes[1];            // 500000
    const int M  = in_sizes[4];            // 64
    const int CR = in_sizes[2] / N;        // 32
    const int CC = in_sizes[3] / N;        // 64
    const int C  = CR + CC;                // 96

    float* roi  = (float*)d_out;                    // [M, C]
    float* skip = roi + (size_t)M * C;              // [N, CR]
    float* sel  = skip + (size_t)N * CR;            // [N]

    float* roi_ws = (float*)d_ws;                   // [M, C] accumulator

    const int nroi = M * C;                         // 6144
    const int nreg = (N + RB - 1) / RB;             // 489

    k0_zero<<<(nroi + BLK - 1) / BLK, BLK, 0, stream>>>(roi_ws, nroi);
    kA_fused<<<nreg, BLK, 0, stream>>>(coords, batch_idx, features, conv,
                                       box_batch, box_min, box_max,
                                       skip, sel, roi_ws, N, M);
    k3_copy<<<(nroi + BLK - 1) / BLK, BLK, 0, stream>>>(roi_ws, roi, nroi);
}

// Round 8
// 54.846 us; speedup vs baseline: 1.2760x; 1.2760x over previous
//
#include <hip/hip_runtime.h>

#define BLK 256
#define VPT 2
#define RB (BLK * VPT)   // 512 rows per block -> 977 blocks (~3.8/CU)

typedef float v4f __attribute__((ext_vector_type(4)));

// ---------------------------------------------------------------------------
// k0: zero roi[M*C] in d_out so kA can atomically accumulate into it.
// ---------------------------------------------------------------------------
__global__ __launch_bounds__(BLK) void k0_zero_roi(float* __restrict__ roi, int n)
{
    const int t = blockIdx.x * BLK + threadIdx.x;
    if (t < n) roi[t] = 0.0f;
}

// ---------------------------------------------------------------------------
// kA: fused. Per region of 512 rows:
//   1) mask 2 voxels/thread vs 64 boxes (one ds_read_b128 per box, packed)
//   2) sel store (regular) + block-local LDS compaction
//   3) ROI phase: 4 waves gather conv/feature rows of hits, atomicAdd -> roi
//   4) skip nt-store burst: zeros except selected rows (~3.5%)
// ---------------------------------------------------------------------------
__global__ __launch_bounds__(BLK) void kA_fused(
    const int* __restrict__ coords,      // [N,3]
    const int* __restrict__ batch_idx,   // [N]
    const float* __restrict__ features,  // [N,32]
    const float* __restrict__ conv,      // [N,64]
    const int* __restrict__ box_batch,   // [M]
    const int* __restrict__ box_min,     // [M,3]
    const int* __restrict__ box_max,     // [M,3]
    float* __restrict__ skip_out,        // [N,32]
    float* __restrict__ sel_out,         // [N]
    float* __restrict__ roi,             // [M,96] pre-zeroed by k0
    int N, int M)
{
    __shared__ int4 sbox[64];            // {lo|hi<<16, y0|y1<<16, z0|z1<<16, -}
    __shared__ float ssel[RB];
    __shared__ int svox[RB];
    __shared__ unsigned long long smask[RB];
    __shared__ int wc[4 * VPT];
    __shared__ int wb[4 * VPT];
    __shared__ int scnt;

    const int t = threadIdx.x;
    const int lane = t & 63;
    const int wid = t >> 6;
    const int base = blockIdx.x * RB;

    // Stage packed box bounds; pad m>=M with an empty range (lo=0xFFFF,hi=0).
    if (t < 64) {
        int w0 = 0xFFFF, w1 = 0, w2 = 0;
        if (t < M) {
            const int b = box_batch[t];
            const int lo = (b << 9) | box_min[t * 3 + 0];
            const int hi = (b << 9) | box_max[t * 3 + 0];
            w0 = lo | (hi << 16);
            w1 = box_min[t * 3 + 1] | (box_max[t * 3 + 1] << 16);
            w2 = box_min[t * 3 + 2] | (box_max[t * 3 + 2] << 16);
        }
        sbox[t] = make_int4(w0, w1, w2, 0);
    }
    __syncthreads();

    // ---- mask: VPT voxels per thread, one b128 per box ----
    int px[VPT], py[VPT], pz[VPT];
    unsigned long long mask[VPT];
    #pragma unroll
    for (int v = 0; v < VPT; ++v) {
        const int i = base + v * BLK + t;
        mask[v] = 0ull;
        if (i < N) {
            const int x = coords[(size_t)i * 3 + 0];
            const int y = coords[(size_t)i * 3 + 1];
            const int z = coords[(size_t)i * 3 + 2];
            px[v] = (batch_idx[i] << 9) | x;
            py[v] = y;  pz[v] = z;
        } else {
            px[v] = -1;  py[v] = -1;  pz[v] = -1;
        }
    }
    #pragma unroll 8
    for (int m = 0; m < 64; ++m) {
        const int4 q = sbox[m];
        const int lo = q.x & 0xFFFF, hi = ((unsigned)q.x) >> 16;
        const int y0 = q.y & 0xFFFF, y1 = ((unsigned)q.y) >> 16;
        const int z0 = q.z & 0xFFFF, z1 = ((unsigned)q.z) >> 16;
        #pragma unroll
        for (int v = 0; v < VPT; ++v) {
            const bool ins = (px[v] >= lo) & (px[v] < hi)
                           & (py[v] >= y0) & (py[v] < y1)
                           & (pz[v] >= z0) & (pz[v] < z1);
            mask[v] |= ins ? (1ull << m) : 0ull;
        }
    }

    // selection output (regular store) + LDS flags
    #pragma unroll
    for (int v = 0; v < VPT; ++v) {
        const int i = base + v * BLK + t;
        const float s = mask[v] ? 1.0f : 0.0f;
        ssel[v * BLK + t] = s;
        if (i < N) sel_out[i] = s;
    }

    // ---- block-local compaction into LDS (deterministic, no atomics) ----
    unsigned long long ball[VPT];
    #pragma unroll
    for (int v = 0; v < VPT; ++v) ball[v] = __ballot(mask[v] != 0ull);
    if (lane == 0) {
        #pragma unroll
        for (int v = 0; v < VPT; ++v) wc[wid * VPT + v] = __popcll(ball[v]);
    }
    __syncthreads();
    if (t == 0) {
        int s = 0;
        #pragma unroll
        for (int k = 0; k < 4 * VPT; ++k) { wb[k] = s; s += wc[k]; }
        scnt = s;
    }
    __syncthreads();
    #pragma unroll
    for (int v = 0; v < VPT; ++v) {
        if (mask[v]) {
            const int pos = wb[wid * VPT + v]
                          + __popcll(ball[v] & ((1ull << lane) - 1ull));
            svox[pos] = base + v * BLK + t;
            smask[pos] = mask[v];
        }
    }
    __syncthreads();

    // ---- ROI phase: 4 waves split this block's hits (R6 champion order) ----
    const int cnt = scnt;
    for (int j = wid; j < cnt; j += 4) {
        const int vox = svox[j];
        unsigned long long mk = smask[j];
        const float cval = conv[(size_t)vox * 64 + lane];
        const float fval = (lane < 32) ? features[(size_t)vox * 32 + lane] : 0.0f;
        while (mk) {
            const int m = __ffsll((long long)mk) - 1;
            mk &= mk - 1;
            atomicAdd(&roi[m * 96 + lane], cval);
            if (lane < 32) atomicAdd(&roi[m * 96 + 64 + lane], fval);
        }
    }

    // ---- skip nt-store burst: zeros except selected rows ----
    const int nrows = min(RB, N - base);
    if (nrows > 0) {
        const v4f* __restrict__ f4 = (const v4f*)features;
        v4f* __restrict__ s4 = (v4f*)skip_out;
        const int total = nrows * 8;           // 8 float4 per 32-float row
        for (int j = t; j < total; j += BLK) {
            const int r = j >> 3;
            const size_t idx = (size_t)base * 8 + j;
            v4f vv = {0.f, 0.f, 0.f, 0.f};
            if (ssel[r] != 0.0f) vv = f4[idx];
            __builtin_nontemporal_store(vv, &s4[idx]);
        }
    }
}

extern "C" void kernel_launch(void* const* d_in, const int* in_sizes, int n_in,
                              void* d_out, int out_size, void* d_ws, size_t ws_size,
                              hipStream_t stream)
{
    const int* coords      = (const int*)d_in[0];
    const int* batch_idx   = (const int*)d_in[1];
    const float* features  = (const float*)d_in[2];
    const float* conv      = (const float*)d_in[3];
    const int* box_batch   = (const int*)d_in[4];
    const int* box_min     = (const int*)d_in[5];
    const int* box_max     = (const int*)d_in[6];

    const int N  = in_sizes[1];            // 500000
    const int M  = in_sizes[4];            // 64
    const int CR = in_sizes[2] / N;        // 32
    const int CC = in_sizes[3] / N;        // 64
    const int C  = CR + CC;                // 96

    float* roi  = (float*)d_out;                    // [M, C]
    float* skip = roi + (size_t)M * C;              // [N, CR]
    float* sel  = skip + (size_t)N * CR;            // [N]

    const int nroi = M * C;                         // 6144
    const int nreg = (N + RB - 1) / RB;             // 977

    k0_zero_roi<<<(nroi + BLK - 1) / BLK, BLK, 0, stream>>>(roi, nroi);
    kA_fused<<<nreg, BLK, 0, stream>>>(coords, batch_idx, features, conv,
                                       box_batch, box_min, box_max,
                                       skip, sel, roi, N, M);
}

// Round 9
// 52.001 us; speedup vs baseline: 1.3459x; 1.0547x over previous
//
#include <hip/hip_runtime.h>

#define BLK 256
#define RB  256   // 1 voxel/thread -> 1954 blocks (~7.6/CU, ~30 waves/CU)

typedef float v4f __attribute__((ext_vector_type(4)));

// ---------------------------------------------------------------------------
// k0: zero roi[M*C] in d_out so kA can atomically accumulate into it.
// ---------------------------------------------------------------------------
__global__ __launch_bounds__(BLK) void k0_zero_roi(float* __restrict__ roi, int n)
{
    const int t = blockIdx.x * BLK + threadIdx.x;
    if (t < n) roi[t] = 0.0f;
}

// ---------------------------------------------------------------------------
// kA: fused, 1 voxel/thread, maximum wave count for outstanding-store depth.
//   1) mask voxel vs 64 boxes (one broadcast ds_read_b128 per box)
//   2) sel store + block-local LDS compaction
//   3) ROI phase: 4 waves gather conv/feature rows of hits, atomicAdd -> roi
//   4) skip nt-store burst: zeros except selected rows (~3.5%)
// ---------------------------------------------------------------------------
__global__ __launch_bounds__(BLK) void kA_fused(
    const int* __restrict__ coords,      // [N,3]
    const int* __restrict__ batch_idx,   // [N]
    const float* __restrict__ features,  // [N,32]
    const float* __restrict__ conv,      // [N,64]
    const int* __restrict__ box_batch,   // [M]
    const int* __restrict__ box_min,     // [M,3]
    const int* __restrict__ box_max,     // [M,3]
    float* __restrict__ skip_out,        // [N,32]
    float* __restrict__ sel_out,         // [N]
    float* __restrict__ roi,             // [M,96] pre-zeroed by k0
    int N, int M)
{
    __shared__ int4 sbox[64];            // {lo|hi<<16, y0|y1<<16, z0|z1<<16, -}
    __shared__ float ssel[RB];
    __shared__ int svox[RB];
    __shared__ unsigned long long smask[RB];
    __shared__ int wc[4];
    __shared__ int wb[4];
    __shared__ int scnt;

    const int t = threadIdx.x;
    const int lane = t & 63;
    const int wid = t >> 6;
    const int base = blockIdx.x * RB;

    // Stage packed box bounds; pad m>=M with an empty range (lo=0xFFFF,hi=0).
    if (t < 64) {
        int w0 = 0xFFFF, w1 = 0, w2 = 0;
        if (t < M) {
            const int b = box_batch[t];
            const int lo = (b << 9) | box_min[t * 3 + 0];
            const int hi = (b << 9) | box_max[t * 3 + 0];
            w0 = lo | (hi << 16);
            w1 = box_min[t * 3 + 1] | (box_max[t * 3 + 1] << 16);
            w2 = box_min[t * 3 + 2] | (box_max[t * 3 + 2] << 16);
        }
        sbox[t] = make_int4(w0, w1, w2, 0);
    }
    __syncthreads();

    // ---- mask: one voxel per thread ----
    const int i = base + t;
    int px = -1, py = -1, pz = -1;
    if (i < N) {
        px = (batch_idx[i] << 9) | coords[(size_t)i * 3 + 0];
        py = coords[(size_t)i * 3 + 1];
        pz = coords[(size_t)i * 3 + 2];
    }
    unsigned long long mask = 0ull;
    #pragma unroll 8
    for (int m = 0; m < 64; ++m) {
        const int4 q = sbox[m];
        const int lo = q.x & 0xFFFF, hi = ((unsigned)q.x) >> 16;
        const int y0 = q.y & 0xFFFF, y1 = ((unsigned)q.y) >> 16;
        const int z0 = q.z & 0xFFFF, z1 = ((unsigned)q.z) >> 16;
        const bool ins = (px >= lo) & (px < hi)
                       & (py >= y0) & (py < y1)
                       & (pz >= z0) & (pz < z1);
        mask |= ins ? (1ull << m) : 0ull;
    }

    // selection output + LDS flag
    const float s = mask ? 1.0f : 0.0f;
    ssel[t] = s;
    if (i < N) sel_out[i] = s;

    // ---- block-local compaction into LDS (deterministic, no atomics) ----
    const unsigned long long ball = __ballot(mask != 0ull);
    if (lane == 0) wc[wid] = __popcll(ball);
    __syncthreads();
    if (t == 0) {
        int acc = 0;
        #pragma unroll
        for (int k = 0; k < 4; ++k) { wb[k] = acc; acc += wc[k]; }
        scnt = acc;
    }
    __syncthreads();
    if (mask) {
        const int pos = wb[wid] + __popcll(ball & ((1ull << lane) - 1ull));
        svox[pos] = i;
        smask[pos] = mask;
    }
    __syncthreads();

    // ---- ROI phase: 4 waves split this block's hits ----
    const int cnt = scnt;
    for (int j = wid; j < cnt; j += 4) {
        const int vox = svox[j];
        unsigned long long mk = smask[j];
        const float cval = conv[(size_t)vox * 64 + lane];
        const float fval = (lane < 32) ? features[(size_t)vox * 32 + lane] : 0.0f;
        while (mk) {
            const int m = __ffsll((long long)mk) - 1;
            mk &= mk - 1;
            atomicAdd(&roi[m * 96 + lane], cval);
            if (lane < 32) atomicAdd(&roi[m * 96 + 64 + lane], fval);
        }
    }

    // ---- skip nt-store burst: zeros except selected rows ----
    const int nrows = min(RB, N - base);
    if (nrows > 0) {
        const v4f* __restrict__ f4 = (const v4f*)features;
        v4f* __restrict__ s4 = (v4f*)skip_out;
        const int total = nrows * 8;           // 8 float4 per 32-float row
        for (int j = t; j < total; j += BLK) {
            const int r = j >> 3;
            const size_t idx = (size_t)base * 8 + j;
            v4f vv = {0.f, 0.f, 0.f, 0.f};
            if (ssel[r] != 0.0f) vv = f4[idx];
            __builtin_nontemporal_store(vv, &s4[idx]);
        }
    }
}

extern "C" void kernel_launch(void* const* d_in, const int* in_sizes, int n_in,
                              void* d_out, int out_size, void* d_ws, size_t ws_size,
                              hipStream_t stream)
{
    const int* coords      = (const int*)d_in[0];
    const int* batch_idx   = (const int*)d_in[1];
    const float* features  = (const float*)d_in[2];
    const float* conv      = (const float*)d_in[3];
    const int* box_batch   = (const int*)d_in[4];
    const int* box_min     = (const int*)d_in[5];
    const int* box_max     = (const int*)d_in[6];

    const int N  = in_sizes[1];            // 500000
    const int M  = in_sizes[4];            // 64
    const int CR = in_sizes[2] / N;        // 32
    const int CC = in_sizes[3] / N;        // 64
    const int C  = CR + CC;                // 96

    float* roi  = (float*)d_out;                    // [M, C]
    float* skip = roi + (size_t)M * C;              // [N, CR]
    float* sel  = skip + (size_t)N * CR;            // [N]

    const int nroi = M * C;                         // 6144
    const int nreg = (N + RB - 1) / RB;             // 1954

    k0_zero_roi<<<(nroi + BLK - 1) / BLK, BLK, 0, stream>>>(roi, nroi);
    kA_fused<<<nreg, BLK, 0, stream>>>(coords, batch_idx, features, conv,
                                       box_batch, box_min, box_max,
                                       skip, sel, roi, N, M);
}

// Round 10
// 51.456 us; speedup vs baseline: 1.3601x; 1.0106x over previous
//
#include <hip/hip_runtime.h>

#define BLK 256
#define RB  256   // 1 voxel/thread -> 1954 blocks (~7.6/CU, ~30 waves/CU)

typedef float v4f __attribute__((ext_vector_type(4)));

// ---------------------------------------------------------------------------
// k0: zero roi[M*C] in d_out so kA can atomically accumulate into it.
// ---------------------------------------------------------------------------
__global__ __launch_bounds__(BLK) void k0_zero_roi(float* __restrict__ roi, int n)
{
    const int t = blockIdx.x * BLK + threadIdx.x;
    if (t < n) roi[t] = 0.0f;
}

// ---------------------------------------------------------------------------
// kA: fused, 1 voxel/thread, max wave count for outstanding-store depth.
//   1) mask voxel vs 64 boxes (one broadcast ds_read_b128 per box)
//   2) block-local LDS compaction
//   3) ROI phase: 4 waves gather conv/feature rows of hits, atomicAdd -> roi
//   4) sel write: cooperative float4 from LDS (dense 1KB/block, no 4B sectors)
//   5) skip nt-store burst: zeros except selected rows (~3.5%)
// ---------------------------------------------------------------------------
__global__ __launch_bounds__(BLK) void kA_fused(
    const int* __restrict__ coords,      // [N,3]
    const int* __restrict__ batch_idx,   // [N]
    const float* __restrict__ features,  // [N,32]
    const float* __restrict__ conv,      // [N,64]
    const int* __restrict__ box_batch,   // [M]
    const int* __restrict__ box_min,     // [M,3]
    const int* __restrict__ box_max,     // [M,3]
    float* __restrict__ skip_out,        // [N,32]
    float* __restrict__ sel_out,         // [N]
    float* __restrict__ roi,             // [M,96] pre-zeroed by k0
    int N, int M)
{
    __shared__ int4 sbox[64];            // {lo|hi<<16, y0|y1<<16, z0|z1<<16, -}
    __shared__ float ssel[RB];
    __shared__ int svox[RB];
    __shared__ unsigned long long smask[RB];
    __shared__ int wc[4];
    __shared__ int wb[4];
    __shared__ int scnt;

    const int t = threadIdx.x;
    const int lane = t & 63;
    const int wid = t >> 6;
    const int base = blockIdx.x * RB;

    // Stage packed box bounds; pad m>=M with an empty range (lo=0xFFFF,hi=0).
    if (t < 64) {
        int w0 = 0xFFFF, w1 = 0, w2 = 0;
        if (t < M) {
            const int b = box_batch[t];
            const int lo = (b << 9) | box_min[t * 3 + 0];
            const int hi = (b << 9) | box_max[t * 3 + 0];
            w0 = lo | (hi << 16);
            w1 = box_min[t * 3 + 1] | (box_max[t * 3 + 1] << 16);
            w2 = box_min[t * 3 + 2] | (box_max[t * 3 + 2] << 16);
        }
        sbox[t] = make_int4(w0, w1, w2, 0);
    }
    __syncthreads();

    // ---- mask: one voxel per thread ----
    const int i = base + t;
    int px = -1, py = -1, pz = -1;
    if (i < N) {
        px = (batch_idx[i] << 9) | coords[(size_t)i * 3 + 0];
        py = coords[(size_t)i * 3 + 1];
        pz = coords[(size_t)i * 3 + 2];
    }
    unsigned long long mask = 0ull;
    #pragma unroll 8
    for (int m = 0; m < 64; ++m) {
        const int4 q = sbox[m];
        const int lo = q.x & 0xFFFF, hi = ((unsigned)q.x) >> 16;
        const int y0 = q.y & 0xFFFF, y1 = ((unsigned)q.y) >> 16;
        const int z0 = q.z & 0xFFFF, z1 = ((unsigned)q.z) >> 16;
        const bool ins = (px >= lo) & (px < hi)
                       & (py >= y0) & (py < y1)
                       & (pz >= z0) & (pz < z1);
        mask |= ins ? (1ull << m) : 0ull;
    }

    ssel[t] = mask ? 1.0f : 0.0f;

    // ---- block-local compaction into LDS (deterministic, no atomics) ----
    const unsigned long long ball = __ballot(mask != 0ull);
    if (lane == 0) wc[wid] = __popcll(ball);
    __syncthreads();
    if (t == 0) {
        int acc = 0;
        #pragma unroll
        for (int k = 0; k < 4; ++k) { wb[k] = acc; acc += wc[k]; }
        scnt = acc;
    }
    __syncthreads();
    if (mask) {
        const int pos = wb[wid] + __popcll(ball & ((1ull << lane) - 1ull));
        svox[pos] = i;
        smask[pos] = mask;
    }
    __syncthreads();

    // ---- sel write: cooperative float4 from LDS (dense sectors) ----
    const int nrows = min(RB, N - base);
    if (nrows == RB) {
        if (t < RB / 4) {
            const v4f sv = { ssel[t * 4 + 0], ssel[t * 4 + 1],
                             ssel[t * 4 + 2], ssel[t * 4 + 3] };
            __builtin_nontemporal_store(sv, &((v4f*)sel_out)[base / 4 + t]);
        }
    } else if (nrows > 0) {
        if (t < nrows) sel_out[base + t] = ssel[t];
    }

    // ---- ROI phase: 4 waves split this block's hits ----
    const int cnt = scnt;
    for (int j = wid; j < cnt; j += 4) {
        const int vox = svox[j];
        unsigned long long mk = smask[j];
        const float cval = conv[(size_t)vox * 64 + lane];
        const float fval = (lane < 32) ? features[(size_t)vox * 32 + lane] : 0.0f;
        while (mk) {
            const int m = __ffsll((long long)mk) - 1;
            mk &= mk - 1;
            atomicAdd(&roi[m * 96 + lane], cval);
            if (lane < 32) atomicAdd(&roi[m * 96 + 64 + lane], fval);
        }
    }

    // ---- skip nt-store burst: zeros except selected rows ----
    if (nrows > 0) {
        const v4f* __restrict__ f4 = (const v4f*)features;
        v4f* __restrict__ s4 = (v4f*)skip_out;
        const int total = nrows * 8;           // 8 float4 per 32-float row
        for (int j = t; j < total; j += BLK) {
            const int r = j >> 3;
            const size_t idx = (size_t)base * 8 + j;
            v4f vv = {0.f, 0.f, 0.f, 0.f};
            if (ssel[r] != 0.0f) vv = f4[idx];
            __builtin_nontemporal_store(vv, &s4[idx]);
        }
    }
}

extern "C" void kernel_launch(void* const* d_in, const int* in_sizes, int n_in,
                              void* d_out, int out_size, void* d_ws, size_t ws_size,
                              hipStream_t stream)
{
    const int* coords      = (const int*)d_in[0];
    const int* batch_idx   = (const int*)d_in[1];
    const float* features  = (const float*)d_in[2];
    const float* conv      = (const float*)d_in[3];
    const int* box_batch   = (const int*)d_in[4];
    const int* box_min     = (const int*)d_in[5];
    const int* box_max     = (const int*)d_in[6];

    const int N  = in_sizes[1];            // 500000
    const int M  = in_sizes[4];            // 64
    const int CR = in_sizes[2] / N;        // 32
    const int CC = in_sizes[3] / N;        // 64
    const int C  = CR + CC;                // 96

    float* roi  = (float*)d_out;                    // [M, C]
    float* skip = roi + (size_t)M * C;              // [N, CR]
    float* sel  = skip + (size_t)N * CR;            // [N]

    const int nroi = M * C;                         // 6144
    const int nreg = (N + RB - 1) / RB;             // 1954

    k0_zero_roi<<<(nroi + BLK - 1) / BLK, BLK, 0, stream>>>(roi, nroi);
    kA_fused<<<nreg, BLK, 0, stream>>>(coords, batch_idx, features, conv,
                                       box_batch, box_min, box_max,
                                       skip, sel, roi, N, M);
}